// Round 13
// baseline (3429.103 us; speedup 1.0000x reference)
//
#include <hip/hip_runtime.h>
#include <hip/hip_fp16.h>
#include <math.h>
#include <cstddef>

#define N_PTS 131072
#define SDIM  512
#define D1    513
#define W0F   0.169f

static constexpr int NITER = 100;
static constexpr int BLK   = 512;            // 8 waves / block
static constexpr int GRID  = 512;            // 2 blocks / CU
static constexpr int WPB   = BLK / 64;       // 8 waves per block
static constexpr int NW    = GRID * WPB;     // 4096 waves
static constexpr int NPAIR = N_PTS / 2;      // 65536 row-pairs
static constexpr int PPW   = NPAIR / NW;     // 16 pairs per wave

struct Ws {
  double colsum[514];          // [0..511] spatial, [512] t-sum, [513] cc-sum (residual)
  double X[514];               // exact w=1 sums: [0..511] sum x_c, [512] T = sum t
  double part[514][GRID];      // column-major per-block partials
  float  meanbuf[2][516];      // [0..511] spatial, [512] time (double-buffered)
  float  t_tab[N_PTS];         // precomputed sqrt(1+|x_i|^2)
};
// fp8 data copy (N_PTS*512 bytes) lives at 256B-aligned offset after Ws in d_ws.

// ---- fp8 e4m3 encode (RNE, flush |x|<2^-6, clamp 448) ----
__device__ __forceinline__ unsigned enc8(float x) {
  unsigned u  = __float_as_uint(x);
  unsigned s  = (u >> 24) & 0x80u;
  unsigned au = u & 0x7fffffffu;
  if (au < 0x3c800000u) return s;                          // |x| < 2^-6 -> +-0
  unsigned r = au + 0x0007ffffu + ((au >> 20) & 1u);       // RNE to 3 mant bits
  unsigned e = r >> 23;
  unsigned m = (r >> 20) & 7u;
  if (e > 135u || (e == 135u && m > 6u)) return s | 0x7Eu; // clamp to 448
  return s | ((e - 120u) << 3) | m;
}

// ---- fp8 e4m3 decode: byte -> f16 bits -> f32 ----
__device__ __forceinline__ unsigned dec8h(unsigned b) {
  unsigned h = ((b & 0x80u) << 8) | ((b & 0x7fu) << 7);
  return (b & 0x7fu) ? (h + 0x2000u) : h;
}
__device__ __forceinline__ float2 dec2(unsigned b0, unsigned b1) {
  union { unsigned u; __half2 h; } c;
  c.u = dec8h(b0) | (dec8h(b1) << 16);
  return __half22float2(c.h);
}
__device__ __forceinline__ float4 dec4(unsigned v) {
  float2 lo = dec2(v & 0xffu, (v >> 8) & 0xffu);
  float2 hi = dec2((v >> 16) & 0xffu, v >> 24);
  return make_float4(lo.x, lo.y, hi.x, hi.y);
}

// ---- mean update (columns c=q*64+l; c<512 spatial, c==512 time) ----
template<bool INIT>
__device__ __forceinline__ void compute_mean(const Ws* __restrict__ ws,
                                             const float* __restrict__ mprev,
                                             int l, float out[9])
{
  if constexpr (INIT) {
    double r[9]; double s2 = 0.0;
    #pragma unroll
    for (int q = 0; q < 9; ++q) {
      int c = q * 64 + l;
      r[q] = (c < D1) ? ws->colsum[c] / (double)N_PTS : 0.0;
      s2 += r[q] * r[q];
    }
    #pragma unroll
    for (int m = 1; m < 64; m <<= 1) s2 += __shfl_xor(s2, m);
    double rt = __shfl(r[8], 0);
    double inv = 1.0 / sqrt(fabs(s2 - 2.0 * rt * rt));
    #pragma unroll
    for (int q = 0; q < 9; ++q) out[q] = (float)(r[q] * inv);
  } else {
    const double W0d = (double)W0F;
    // exact correction terms from X
    double xdm = 0.0;
    #pragma unroll
    for (int q = 0; q < 8; ++q) {
      int c = q * 64 + l;                       // always < 512
      xdm += ws->X[c] * (double)mprev[c];
    }
    #pragma unroll
    for (int m = 1; m < 64; m <<= 1) xdm += __shfl_xor(xdm, m);
    const double T   = ws->X[512];
    const double m0p = (double)mprev[512];

    double sv[9];
    #pragma unroll
    for (int q = 0; q < 9; ++q) {
      int c = q * 64 + l;
      if (c < 512)       sv[q] = ws->colsum[c]   + W0d * ws->X[c];
      else if (c == 512) sv[q] = ws->colsum[512] + W0d * T;
      else               sv[q] = 0.0;
    }
    double cc = ws->colsum[513] + W0d * (m0p * T - xdm);

    double mv[9], yv[9]; double sy = 0.0;
    #pragma unroll
    for (int q = 0; q < 9; ++q) {
      int c = q * 64 + l;
      mv[q] = 0.0; yv[q] = 0.0;
      if (c < D1) {
        double m = (double)mprev[c];
        double y = 0.02 * (sv[q] - cc * m) / (double)N_PTS;  // y = -R*g
        mv[q] = m; yv[q] = y;
        sy += y * y;
      }
    }
    #pragma unroll
    for (int m = 1; m < 64; m <<= 1) sy += __shfl_xor(sy, m);
    double yt = __shfl(yv[8], 0);
    double n = sqrt(fabs(sy - 2.0 * yt * yt));
    n = fmax(n, 1e-5);
    double ch = cosh(n);
    double sn = (n < 1e-4) ? (1.0 + n * n / 6.0) : (sinh(n) / n);
    double nm[9]; double s2 = 0.0;
    #pragma unroll
    for (int q = 0; q < 9; ++q) { nm[q] = ch * mv[q] + sn * yv[q]; s2 += nm[q] * nm[q]; }
    #pragma unroll
    for (int m = 1; m < 64; m <<= 1) s2 += __shfl_xor(s2, m);
    double nt = __shfl(nm[8], 0);
    double inv = 1.0 / sqrt(fabs(s2 - 2.0 * nt * nt));
    #pragma unroll
    for (int q = 0; q < 9; ++q) out[q] = (float)(nm[q] * inv);
  }
}

// ================= INIT: f32 read -> t_tab + fp8 copy + w=1 partials =================
__global__ __launch_bounds__(BLK, 4)
void init_kernel(const float* __restrict__ data, unsigned char* __restrict__ h8,
                 Ws* __restrict__ ws)
{
  const int l    = threadIdx.x & 63;
  const int sl   = l & 31;
  const int half = l >> 5;
  const int wid  = threadIdx.x >> 6;
  const int gw   = blockIdx.x * WPB + wid;

  float accf[16] = {};
  double acc_t = 0.0;
  const int p0 = gw * PPW;

  float4 v0, v1, v2, v3, n0, n1, n2, n3;
  {
    const float4* f4 = (const float4*)(data + (size_t)(2 * p0 + half) * SDIM);
    v0 = f4[2*sl]; v1 = f4[2*sl+1]; v2 = f4[64+2*sl]; v3 = f4[64+2*sl+1];
  }

  for (int k = 0; k < PPW; ++k) {
    if (k + 1 < PPW) {
      const float4* f4 = (const float4*)(data + (size_t)(2 * (p0 + k + 1) + half) * SDIM);
      n0 = f4[2*sl]; n1 = f4[2*sl+1]; n2 = f4[64+2*sl]; n3 = f4[64+2*sl+1];
    } else { n0 = v0; n1 = v1; n2 = v2; n3 = v3; }

    const int row = 2 * (p0 + k) + half;

    // fp8 copy: cols [8sl..8sl+8) and [256+8sl..+8) as two uint2 stores
    {
      uint2 pa, pb;
      pa.x = enc8(v0.x) | (enc8(v0.y) << 8) | (enc8(v0.z) << 16) | (enc8(v0.w) << 24);
      pa.y = enc8(v1.x) | (enc8(v1.y) << 8) | (enc8(v1.z) << 16) | (enc8(v1.w) << 24);
      pb.x = enc8(v2.x) | (enc8(v2.y) << 8) | (enc8(v2.z) << 16) | (enc8(v2.w) << 24);
      pb.y = enc8(v3.x) | (enc8(v3.y) << 8) | (enc8(v3.z) << 16) | (enc8(v3.w) << 24);
      uint2* hb = (uint2*)(h8 + (size_t)row * SDIM);
      hb[sl] = pa; hb[32 + sl] = pb;
    }

    float sqa = v0.x * v0.x;
    sqa = fmaf(v0.y, v0.y, sqa); sqa = fmaf(v0.z, v0.z, sqa); sqa = fmaf(v0.w, v0.w, sqa);
    sqa = fmaf(v1.x, v1.x, sqa); sqa = fmaf(v1.y, v1.y, sqa);
    sqa = fmaf(v1.z, v1.z, sqa); sqa = fmaf(v1.w, v1.w, sqa);
    float sqb = v2.x * v2.x;
    sqb = fmaf(v2.y, v2.y, sqb); sqb = fmaf(v2.z, v2.z, sqb); sqb = fmaf(v2.w, v2.w, sqb);
    sqb = fmaf(v3.x, v3.x, sqb); sqb = fmaf(v3.y, v3.y, sqb);
    sqb = fmaf(v3.z, v3.z, sqb); sqb = fmaf(v3.w, v3.w, sqb);
    float sq = sqa + sqb;
    #pragma unroll
    for (int m = 1; m < 32; m <<= 1) sq += __shfl_xor(sq, m);

    float t = sqrtf(1.0f + sq);
    if (sl == 0) { ws->t_tab[row] = t; acc_t += (double)t; }

    accf[0]  += v0.x; accf[1]  += v0.y; accf[2]  += v0.z; accf[3]  += v0.w;
    accf[4]  += v1.x; accf[5]  += v1.y; accf[6]  += v1.z; accf[7]  += v1.w;
    accf[8]  += v2.x; accf[9]  += v2.y; accf[10] += v2.z; accf[11] += v2.w;
    accf[12] += v3.x; accf[13] += v3.y; accf[14] += v3.z; accf[15] += v3.w;

    v0 = n0; v1 = n1; v2 = n2; v3 = n3;
  }

  #pragma unroll
  for (int i = 0; i < 16; ++i) accf[i] += __shfl_xor(accf[i], 32);
  acc_t += __shfl_xor(acc_t, 32);

  __shared__ double s_red[WPB][514];
  if (half == 0) {
    #pragma unroll
    for (int i = 0; i < 8; ++i) {
      s_red[wid][8*sl + i]       = (double)accf[i];
      s_red[wid][256 + 8*sl + i] = (double)accf[8 + i];
    }
  }
  if (l == 0) { s_red[wid][512] = acc_t; s_red[wid][513] = 0.0; }
  __syncthreads();

  for (int c = threadIdx.x; c < 514; c += BLK) {
    double s = 0.0;
    #pragma unroll
    for (int w2 = 0; w2 < WPB; ++w2) s += s_red[w2][c];
    ws->part[c][blockIdx.x] = s;
  }
}

// ===== ITER: fused mean prologue + fp8 residual stream (coef = w - W0) ================
template<bool FIRST>
__global__ __launch_bounds__(BLK, 4)
void iter_kernel(const unsigned char* __restrict__ h8, Ws* __restrict__ ws,
                 const float* __restrict__ mprev, float* __restrict__ mnext)
{
  const int l    = threadIdx.x & 63;
  const int sl   = l & 31;
  const int half = l >> 5;
  const int wid  = threadIdx.x >> 6;
  const int gw   = blockIdx.x * WPB + wid;
  const int p0   = gw * PPW;

#define LDH8(R, p) do {                                                        \
    const uint4* b_ = (const uint4*)(h8 + (size_t)(2 * (p) + half) * SDIM);    \
    R = b_[sl];                                                                \
  } while (0)

  // pre-issue first two pair-loads to cover the prologue
  uint4 Aa, Ba, Pa, Qa, Ua, Va;
  LDH8(Aa, p0 + 0);
  LDH8(Ba, p0 + 1);

  // prologue: wave 0 computes this iteration's mean; block 0 publishes it
  __shared__ __align__(16) float s_mean[516];
  if (threadIdx.x < 64) {
    float outm[9];
    compute_mean<FIRST>(ws, mprev, threadIdx.x, outm);
    #pragma unroll
    for (int q = 0; q < 9; ++q) {
      int c = q * 64 + threadIdx.x;
      if (c < D1) {
        s_mean[c] = outm[q];
        if (blockIdx.x == 0) mnext[c] = outm[q];
      }
    }
  }
  __syncthreads();

  const float m0 = s_mean[512];
  const float4* mp4 = (const float4*)s_mean;                 // lane covers cols 16sl..+15
  const float4 mk0 = mp4[4*sl + 0], mk1 = mp4[4*sl + 1];
  const float4 mk2 = mp4[4*sl + 2], mk3 = mp4[4*sl + 3];

  float accf[16] = {};
  double acc_t = 0.0, acc_cc = 0.0;
  const float* __restrict__ ttab = ws->t_tab;

  LDH8(Pa, p0 + 2);
  LDH8(Qa, p0 + 3);
  Ua = Aa; Va = Ba;

  for (int kk = 0; kk < PPW; kk += 2) {
    if (kk + 4 < PPW) {
      LDH8(Ua, p0 + kk + 4);
      LDH8(Va, p0 + kk + 5);
    }
    const float tA = ttab[2 * (p0 + kk)     + half];
    const float tB = ttab[2 * (p0 + kk + 1) + half];

    // decode both pairs (16 f32 each)
    float4 a0 = dec4(Aa.x), a1 = dec4(Aa.y), a2 = dec4(Aa.z), a3 = dec4(Aa.w);
    float4 b0 = dec4(Ba.x), b1 = dec4(Ba.y), b2 = dec4(Ba.z), b3 = dec4(Ba.w);

    // dot trees
    float dA = a0.x * mk0.x;
    dA = fmaf(a0.y, mk0.y, dA); dA = fmaf(a0.z, mk0.z, dA); dA = fmaf(a0.w, mk0.w, dA);
    dA = fmaf(a1.x, mk1.x, dA); dA = fmaf(a1.y, mk1.y, dA);
    dA = fmaf(a1.z, mk1.z, dA); dA = fmaf(a1.w, mk1.w, dA);
    float dA2 = a2.x * mk2.x;
    dA2 = fmaf(a2.y, mk2.y, dA2); dA2 = fmaf(a2.z, mk2.z, dA2); dA2 = fmaf(a2.w, mk2.w, dA2);
    dA2 = fmaf(a3.x, mk3.x, dA2); dA2 = fmaf(a3.y, mk3.y, dA2);
    dA2 = fmaf(a3.z, mk3.z, dA2); dA2 = fmaf(a3.w, mk3.w, dA2);
    float dotA = dA + dA2;

    float dB = b0.x * mk0.x;
    dB = fmaf(b0.y, mk0.y, dB); dB = fmaf(b0.z, mk0.z, dB); dB = fmaf(b0.w, mk0.w, dB);
    dB = fmaf(b1.x, mk1.x, dB); dB = fmaf(b1.y, mk1.y, dB);
    dB = fmaf(b1.z, mk1.z, dB); dB = fmaf(b1.w, mk1.w, dB);
    float dB2 = b2.x * mk2.x;
    dB2 = fmaf(b2.y, mk2.y, dB2); dB2 = fmaf(b2.z, mk2.z, dB2); dB2 = fmaf(b2.w, mk2.w, dB2);
    dB2 = fmaf(b3.x, mk3.x, dB2); dB2 = fmaf(b3.y, mk3.y, dB2);
    dB2 = fmaf(b3.z, mk3.z, dB2); dB2 = fmaf(b3.w, mk3.w, dB2);
    float dotB = dB + dB2;

    #pragma unroll
    for (int m = 1; m < 32; m <<= 1) {
      dotA += __shfl_xor(dotA, m);
      dotB += __shfl_xor(dotB, m);
    }

    const float aA = fmaf(m0, tA, -dotA);
    const float aB = fmaf(m0, tB, -dotB);
    const float xA = fmaxf(aA, 1.0f + 1e-5f);
    const float xB = fmaxf(aB, 1.0f + 1e-5f);
    const float sA = sqrtf(fmaf(xA, xA, -1.0f));
    const float sB = sqrtf(fmaf(xB, xB, -1.0f));
    const float wA = logf(xA + sA) / sA;
    const float wB = logf(xB + sB) / sB;
    const float cA = wA - W0F;
    const float cB = wB - W0F;
    if (sl == 0) {
      acc_cc += fma((double)cA, (double)xA, (double)cB * (double)xB);
      acc_t  += fma((double)cA, (double)tA, (double)cB * (double)tB);
    }

    accf[0]  = fmaf(cA, a0.x, fmaf(cB, b0.x, accf[0]));
    accf[1]  = fmaf(cA, a0.y, fmaf(cB, b0.y, accf[1]));
    accf[2]  = fmaf(cA, a0.z, fmaf(cB, b0.z, accf[2]));
    accf[3]  = fmaf(cA, a0.w, fmaf(cB, b0.w, accf[3]));
    accf[4]  = fmaf(cA, a1.x, fmaf(cB, b1.x, accf[4]));
    accf[5]  = fmaf(cA, a1.y, fmaf(cB, b1.y, accf[5]));
    accf[6]  = fmaf(cA, a1.z, fmaf(cB, b1.z, accf[6]));
    accf[7]  = fmaf(cA, a1.w, fmaf(cB, b1.w, accf[7]));
    accf[8]  = fmaf(cA, a2.x, fmaf(cB, b2.x, accf[8]));
    accf[9]  = fmaf(cA, a2.y, fmaf(cB, b2.y, accf[9]));
    accf[10] = fmaf(cA, a2.z, fmaf(cB, b2.z, accf[10]));
    accf[11] = fmaf(cA, a2.w, fmaf(cB, b2.w, accf[11]));
    accf[12] = fmaf(cA, a3.x, fmaf(cB, b3.x, accf[12]));
    accf[13] = fmaf(cA, a3.y, fmaf(cB, b3.y, accf[13]));
    accf[14] = fmaf(cA, a3.z, fmaf(cB, b3.z, accf[14]));
    accf[15] = fmaf(cA, a3.w, fmaf(cB, b3.w, accf[15]));

    Aa = Pa; Ba = Qa;
    Pa = Ua; Qa = Va;
  }
#undef LDH8

  #pragma unroll
  for (int i = 0; i < 16; ++i) accf[i] += __shfl_xor(accf[i], 32);
  acc_t  += __shfl_xor(acc_t, 32);
  acc_cc += __shfl_xor(acc_cc, 32);

  __shared__ double s_red[WPB][514];
  if (half == 0) {
    #pragma unroll
    for (int i = 0; i < 16; ++i) s_red[wid][16*sl + i] = (double)accf[i];
  }
  if (l == 0) { s_red[wid][512] = acc_t; s_red[wid][513] = acc_cc; }
  __syncthreads();

  for (int c = threadIdx.x; c < 514; c += BLK) {
    double s = 0.0;
    #pragma unroll
    for (int w2 = 0; w2 < WPB; ++w2) s += s_red[w2][c];
    ws->part[c][blockIdx.x] = s;
  }
}

// ---------------- per-column reduce (optionally persist exact X after init) ----------
template<bool WRITE_X>
__global__ __launch_bounds__(64)
void colreduce_kernel(Ws* __restrict__ ws)
{
  const int c = blockIdx.x;
  const int l = threadIdx.x;
  const double* col = ws->part[c];
  double s = 0.0;
  #pragma unroll
  for (int k = 0; k < GRID / 64; ++k) s += col[l + 64 * k];
  #pragma unroll
  for (int m = 1; m < 64; m <<= 1) s += __shfl_xor(s, m);
  if (l == 0) {
    ws->colsum[c] = s;
    if constexpr (WRITE_X) ws->X[c] = s;
  }
}

// ---------------- final mean (one wave), after the last colreduce ----------------
__global__ __launch_bounds__(64)
void final_kernel(Ws* __restrict__ ws, const float* __restrict__ mprev,
                  float* __restrict__ mnext)
{
  float outm[9];
  compute_mean<false>(ws, mprev, threadIdx.x, outm);
  #pragma unroll
  for (int q = 0; q < 9; ++q) {
    int c = q * 64 + threadIdx.x;
    if (c < D1) mnext[c] = outm[q];
  }
}

__global__ void write_out_kernel(const float* __restrict__ mean, float* __restrict__ out)
{
  int i = threadIdx.x;
  if (i < SDIM) out[i] = mean[i];   // spatial at [0..511]
}

extern "C" void kernel_launch(void* const* d_in, const int* in_sizes, int n_in,
                              void* d_out, int out_size, void* d_ws, size_t ws_size,
                              hipStream_t stream)
{
  (void)in_sizes; (void)n_in; (void)out_size; (void)ws_size;
  const float* data = (const float*)d_in[0];
  Ws* ws = (Ws*)d_ws;

  const size_t hoff = (sizeof(Ws) + 255) & ~(size_t)255;
  unsigned char* h8 = (unsigned char*)d_ws + hoff;

  float* M0 = (float*)((char*)d_ws + offsetof(Ws, meanbuf));
  float* M1 = M0 + 516;

  init_kernel<<<dim3(GRID), dim3(BLK), 0, stream>>>(data, h8, ws);
  colreduce_kernel<true><<<dim3(514), dim3(64), 0, stream>>>(ws);   // colsum + X

  // iter #0: prologue computes mean_0 (INIT semantics) -> M0
  iter_kernel<true><<<dim3(GRID), dim3(BLK), 0, stream>>>(h8, ws, M1, M0);
  colreduce_kernel<false><<<dim3(514), dim3(64), 0, stream>>>(ws);

  for (int it = 1; it < NITER; ++it) {
    const float* mp = (((it + 1) & 1) == 0) ? M0 : M1;
    float*       mn = ((it & 1) == 0) ? M0 : M1;
    iter_kernel<false><<<dim3(GRID), dim3(BLK), 0, stream>>>(h8, ws, mp, mn);
    colreduce_kernel<false><<<dim3(514), dim3(64), 0, stream>>>(ws);
  }

  // mean_100 from the last colreduce + mean_99 (it=99 wrote M1)
  final_kernel<<<dim3(1), dim3(64), 0, stream>>>(ws, M1, M0);
  write_out_kernel<<<dim3(1), dim3(512), 0, stream>>>(M0, (float*)d_out);
}

// Round 14
// 3139.411 us; speedup vs baseline: 1.0923x; 1.0923x over previous
//
#include <hip/hip_runtime.h>
#include <hip/hip_fp16.h>
#include <math.h>
#include <cstddef>

#define N_PTS 131072
#define SDIM  512
#define D1    513

static constexpr int NITER = 100;
static constexpr int BLK   = 512;            // 8 waves / block
static constexpr int GRID  = 512;            // 2 blocks / CU
static constexpr int WPB   = BLK / 64;       // 8 waves per block
static constexpr int NW    = GRID * WPB;     // 4096 waves
static constexpr int NPAIR = N_PTS / 2;      // 65536 row-pairs
static constexpr int PPW   = NPAIR / NW;     // 16 pairs per wave

struct Ws {
  double colsum[514];          // [0..511] spatial, [512] t-sum, [513] cc-sum
  double part[514][GRID];      // column-major per-block partials
  float  meanbuf[2][516];      // [0..511] spatial, [512] time (double-buffered)
  float  t_tab[N_PTS];         // precomputed sqrt(1+|x_i|^2)
};
// fp16 data copy lives at 256B-aligned offset after Ws in d_ws.

__device__ __forceinline__ float2 cvt2(unsigned u) {
  union { unsigned u; __half2 h; } c; c.u = u; return __half22float2(c.h);
}
__device__ __forceinline__ unsigned pack2(float a, float b) {
  union { unsigned u; __half2 h; } c; c.h = __floats2half2_rn(a, b); return c.u;
}

// ---- mean update, all-f32 (series cosh/sinh; no f64 libcalls) ----
// columns c=q*64+l; c<512 spatial, c==512 time
template<bool INIT>
__device__ __forceinline__ void compute_mean(const Ws* __restrict__ ws,
                                             const float* __restrict__ mprev,
                                             int l, float out[9])
{
  if constexpr (INIT) {
    float r[9]; float s2 = 0.f;
    #pragma unroll
    for (int q = 0; q < 9; ++q) {
      int c = q * 64 + l;
      r[q] = (c < D1) ? (float)(ws->colsum[c] * (1.0 / (double)N_PTS)) : 0.f;
      s2 += r[q] * r[q];
    }
    #pragma unroll
    for (int m = 1; m < 64; m <<= 1) s2 += __shfl_xor(s2, m);
    float rt = __shfl(r[8], 0);
    float inv = 1.f / sqrtf(fabsf(s2 - 2.f * rt * rt));
    #pragma unroll
    for (int q = 0; q < 9; ++q) out[q] = r[q] * inv;
  } else {
    const float cc = (float)ws->colsum[513];
    float mv[9], yv[9]; float sy = 0.f;
    #pragma unroll
    for (int q = 0; q < 9; ++q) {
      int c = q * 64 + l;
      mv[q] = 0.f; yv[q] = 0.f;
      if (c < D1) {
        float m  = mprev[c];
        float sv = (float)ws->colsum[c];
        float y  = 0.02f * fmaf(-cc, m, sv) * (1.f / (float)N_PTS);  // y = -R*g
        mv[q] = m; yv[q] = y;
        sy = fmaf(y, y, sy);
      }
    }
    #pragma unroll
    for (int m = 1; m < 64; m <<= 1) sy += __shfl_xor(sy, m);
    float yt = __shfl(yv[8], 0);
    float n = sqrtf(fabsf(sy - 2.f * yt * yt));
    n = fmaxf(n, 1e-5f);
    float ch, sn;
    if (n < 0.25f) {                       // wave-uniform branch; n is tiny in practice
      float nn = n * n;
      ch = 1.f + nn * (0.5f      + nn * (1.f/24.f  + nn * (1.f/720.f)));
      sn = 1.f + nn * (1.f/6.f   + nn * (1.f/120.f + nn * (1.f/5040.f)));
    } else {
      float e = expf(n), ei = 1.f / e;
      ch = 0.5f * (e + ei);
      sn = 0.5f * (e - ei) / n;
    }
    float nm[9]; float s2 = 0.f;
    #pragma unroll
    for (int q = 0; q < 9; ++q) {
      nm[q] = fmaf(ch, mv[q], sn * yv[q]);
      s2 = fmaf(nm[q], nm[q], s2);
    }
    #pragma unroll
    for (int m = 1; m < 64; m <<= 1) s2 += __shfl_xor(s2, m);
    float nt = __shfl(nm[8], 0);
    float inv = 1.f / sqrtf(fabsf(s2 - 2.f * nt * nt));
    #pragma unroll
    for (int q = 0; q < 9; ++q) out[q] = nm[q] * inv;
  }
}

// ================= INIT: f32 read -> t_tab + fp16 copy + w=1 partials =================
__global__ __launch_bounds__(BLK, 4)
void init_kernel(const float* __restrict__ data, __half* __restrict__ hdata,
                 Ws* __restrict__ ws)
{
  const int l    = threadIdx.x & 63;
  const int sl   = l & 31;
  const int half = l >> 5;
  const int wid  = threadIdx.x >> 6;
  const int gw   = blockIdx.x * WPB + wid;

  float accf[16] = {};
  double acc_t = 0.0;

  const int p0 = gw * PPW;

  float4 v0, v1, v2, v3, n0, n1, n2, n3;
  {
    const float4* f4 = (const float4*)(data + (size_t)(2 * p0 + half) * SDIM);
    v0 = f4[2*sl]; v1 = f4[2*sl+1]; v2 = f4[64+2*sl]; v3 = f4[64+2*sl+1];
  }

  for (int k = 0; k < PPW; ++k) {
    if (k + 1 < PPW) {
      const float4* f4 = (const float4*)(data + (size_t)(2 * (p0 + k + 1) + half) * SDIM);
      n0 = f4[2*sl]; n1 = f4[2*sl+1]; n2 = f4[64+2*sl]; n3 = f4[64+2*sl+1];
    } else { n0 = v0; n1 = v1; n2 = v2; n3 = v3; }

    const int row = 2 * (p0 + k) + half;

    {
      uint4 ua, ub;
      ua.x = pack2(v0.x, v0.y); ua.y = pack2(v0.z, v0.w);
      ua.z = pack2(v1.x, v1.y); ua.w = pack2(v1.z, v1.w);
      ub.x = pack2(v2.x, v2.y); ub.y = pack2(v2.z, v2.w);
      ub.z = pack2(v3.x, v3.y); ub.w = pack2(v3.z, v3.w);
      uint4* hb = (uint4*)(hdata + (size_t)row * SDIM);
      hb[sl] = ua; hb[32 + sl] = ub;
    }

    float sqa = v0.x * v0.x;
    sqa = fmaf(v0.y, v0.y, sqa); sqa = fmaf(v0.z, v0.z, sqa); sqa = fmaf(v0.w, v0.w, sqa);
    sqa = fmaf(v1.x, v1.x, sqa); sqa = fmaf(v1.y, v1.y, sqa);
    sqa = fmaf(v1.z, v1.z, sqa); sqa = fmaf(v1.w, v1.w, sqa);
    float sqb = v2.x * v2.x;
    sqb = fmaf(v2.y, v2.y, sqb); sqb = fmaf(v2.z, v2.z, sqb); sqb = fmaf(v2.w, v2.w, sqb);
    sqb = fmaf(v3.x, v3.x, sqb); sqb = fmaf(v3.y, v3.y, sqb);
    sqb = fmaf(v3.z, v3.z, sqb); sqb = fmaf(v3.w, v3.w, sqb);
    float sq = sqa + sqb;
    #pragma unroll
    for (int m = 1; m < 32; m <<= 1) sq += __shfl_xor(sq, m);

    float t = sqrtf(1.0f + sq);
    if (sl == 0) { ws->t_tab[row] = t; acc_t += (double)t; }

    accf[0]  += v0.x; accf[1]  += v0.y; accf[2]  += v0.z; accf[3]  += v0.w;
    accf[4]  += v1.x; accf[5]  += v1.y; accf[6]  += v1.z; accf[7]  += v1.w;
    accf[8]  += v2.x; accf[9]  += v2.y; accf[10] += v2.z; accf[11] += v2.w;
    accf[12] += v3.x; accf[13] += v3.y; accf[14] += v3.z; accf[15] += v3.w;

    v0 = n0; v1 = n1; v2 = n2; v3 = n3;
  }

  #pragma unroll
  for (int i = 0; i < 16; ++i) accf[i] += __shfl_xor(accf[i], 32);
  acc_t += __shfl_xor(acc_t, 32);

  __shared__ double s_red[WPB][514];
  if (half == 0) {
    #pragma unroll
    for (int i = 0; i < 8; ++i) {
      s_red[wid][8*sl + i]       = (double)accf[i];
      s_red[wid][256 + 8*sl + i] = (double)accf[8 + i];
    }
  }
  if (l == 0) { s_red[wid][512] = acc_t; s_red[wid][513] = 0.0; }
  __syncthreads();

  for (int c = threadIdx.x; c < 514; c += BLK) {
    double s = 0.0;
    #pragma unroll
    for (int w2 = 0; w2 < WPB; ++w2) s += s_red[w2][c];
    ws->part[c][blockIdx.x] = s;
  }
}

// ===== ITER: fused f32 mean prologue + fp16 stream, 2 pairs/step, t 1-step pipeline ===
template<bool FIRST>
__global__ __launch_bounds__(BLK, 4)
void iter_kernel(const __half* __restrict__ hdata, Ws* __restrict__ ws,
                 const float* __restrict__ mprev, float* __restrict__ mnext)
{
  const int l    = threadIdx.x & 63;
  const int sl   = l & 31;
  const int half = l >> 5;
  const int wid  = threadIdx.x >> 6;
  const int gw   = blockIdx.x * WPB + wid;

  const int p0 = gw * PPW;

#define LDH(Ra, Rb, p) do {                                                   \
    const uint4* b_ = (const uint4*)(hdata + (size_t)(2 * (p) + half) * SDIM);\
    Ra = b_[sl]; Rb = b_[32 + sl];                                            \
  } while (0)

  // pre-issue the first two pair-loads; they cover the prologue latency
  uint4 Aa, Ab, Ba, Bb, Pa, Pb, Qa, Qb, Ra, Rb, Sa, Sb;
  LDH(Aa, Ab, p0 + 0);
  LDH(Ba, Bb, p0 + 1);

  // prologue: wave 0 computes this iteration's mean (f32, no libcalls);
  // block 0 publishes it for the next iteration.
  __shared__ __align__(16) float s_mean[516];
  if (threadIdx.x < 64) {
    float outm[9];
    compute_mean<FIRST>(ws, mprev, threadIdx.x, outm);
    #pragma unroll
    for (int q = 0; q < 9; ++q) {
      int c = q * 64 + threadIdx.x;
      if (c < D1) {
        s_mean[c] = outm[q];
        if (blockIdx.x == 0) mnext[c] = outm[q];
      }
    }
  }
  __syncthreads();

  const float m0 = s_mean[512];
  const float4* mp4 = (const float4*)s_mean;                   // aligned: spatial at 0
  const float4 mkA0 = mp4[2*sl],      mkA1 = mp4[2*sl + 1];    // cols 8sl..+8
  const float4 mkB0 = mp4[64 + 2*sl], mkB1 = mp4[64 + 2*sl + 1];

  float accf[16] = {};
  double acc_t = 0.0, acc_cc = 0.0;
  const float* __restrict__ ttab = ws->t_tab;

  LDH(Pa, Pb, p0 + 2);
  LDH(Qa, Qb, p0 + 3);
  Ra = Aa; Rb = Ab; Sa = Ba; Sb = Bb;

  // t-value 1-step register pipeline
  float tAc = ttab[2 * p0 + half];
  float tBc = ttab[2 * (p0 + 1) + half];

  for (int kk = 0; kk < PPW; kk += 2) {
    if (kk + 4 < PPW) {
      LDH(Ra, Rb, p0 + kk + 4);
      LDH(Sa, Sb, p0 + kk + 5);
    }
    float tAn = 0.f, tBn = 0.f;
    if (kk + 2 < PPW) {
      tAn = ttab[2 * (p0 + kk + 2) + half];
      tBn = ttab[2 * (p0 + kk + 3) + half];
    }
    const float tA = tAc;
    const float tB = tBc;

    float2 f;
    f = cvt2(Aa.x); float dA  = f.x * mkA0.x;        dA  = fmaf(f.y, mkA0.y, dA);
    f = cvt2(Aa.y); dA  = fmaf(f.x, mkA0.z, dA);     dA  = fmaf(f.y, mkA0.w, dA);
    f = cvt2(Aa.z); dA  = fmaf(f.x, mkA1.x, dA);     dA  = fmaf(f.y, mkA1.y, dA);
    f = cvt2(Aa.w); dA  = fmaf(f.x, mkA1.z, dA);     dA  = fmaf(f.y, mkA1.w, dA);
    f = cvt2(Ab.x); float dA2 = f.x * mkB0.x;        dA2 = fmaf(f.y, mkB0.y, dA2);
    f = cvt2(Ab.y); dA2 = fmaf(f.x, mkB0.z, dA2);    dA2 = fmaf(f.y, mkB0.w, dA2);
    f = cvt2(Ab.z); dA2 = fmaf(f.x, mkB1.x, dA2);    dA2 = fmaf(f.y, mkB1.y, dA2);
    f = cvt2(Ab.w); dA2 = fmaf(f.x, mkB1.z, dA2);    dA2 = fmaf(f.y, mkB1.w, dA2);
    float dotA = dA + dA2;

    f = cvt2(Ba.x); float dB  = f.x * mkA0.x;        dB  = fmaf(f.y, mkA0.y, dB);
    f = cvt2(Ba.y); dB  = fmaf(f.x, mkA0.z, dB);     dB  = fmaf(f.y, mkA0.w, dB);
    f = cvt2(Ba.z); dB  = fmaf(f.x, mkA1.x, dB);     dB  = fmaf(f.y, mkA1.y, dB);
    f = cvt2(Ba.w); dB  = fmaf(f.x, mkA1.z, dB);     dB  = fmaf(f.y, mkA1.w, dB);
    f = cvt2(Bb.x); float dB2 = f.x * mkB0.x;        dB2 = fmaf(f.y, mkB0.y, dB2);
    f = cvt2(Bb.y); dB2 = fmaf(f.x, mkB0.z, dB2);    dB2 = fmaf(f.y, mkB0.w, dB2);
    f = cvt2(Bb.z); dB2 = fmaf(f.x, mkB1.x, dB2);    dB2 = fmaf(f.y, mkB1.y, dB2);
    f = cvt2(Bb.w); dB2 = fmaf(f.x, mkB1.z, dB2);    dB2 = fmaf(f.y, mkB1.w, dB2);
    float dotB = dB + dB2;

    #pragma unroll
    for (int m = 1; m < 32; m <<= 1) {
      dotA += __shfl_xor(dotA, m);
      dotB += __shfl_xor(dotB, m);
    }

    const float aA = fmaf(m0, tA, -dotA);
    const float aB = fmaf(m0, tB, -dotB);
    const float xA = fmaxf(aA, 1.0f + 1e-5f);
    const float xB = fmaxf(aB, 1.0f + 1e-5f);
    const float sA = sqrtf(fmaf(xA, xA, -1.0f));
    const float sB = sqrtf(fmaf(xB, xB, -1.0f));
    const float ddA = logf(xA + sA);
    const float ddB = logf(xB + sB);
    const float wA = ddA / sA;
    const float wB = ddB / sB;
    if (sl == 0) {
      acc_cc += fma((double)wA, (double)xA, (double)wB * (double)xB);
      acc_t  += fma((double)wA, (double)tA, (double)wB * (double)tB);
    }

    float2 a0, a1;
    a0 = cvt2(Aa.x); a1 = cvt2(Ba.x);
    accf[0]  = fmaf(wA, a0.x, fmaf(wB, a1.x, accf[0]));
    accf[1]  = fmaf(wA, a0.y, fmaf(wB, a1.y, accf[1]));
    a0 = cvt2(Aa.y); a1 = cvt2(Ba.y);
    accf[2]  = fmaf(wA, a0.x, fmaf(wB, a1.x, accf[2]));
    accf[3]  = fmaf(wA, a0.y, fmaf(wB, a1.y, accf[3]));
    a0 = cvt2(Aa.z); a1 = cvt2(Ba.z);
    accf[4]  = fmaf(wA, a0.x, fmaf(wB, a1.x, accf[4]));
    accf[5]  = fmaf(wA, a0.y, fmaf(wB, a1.y, accf[5]));
    a0 = cvt2(Aa.w); a1 = cvt2(Ba.w);
    accf[6]  = fmaf(wA, a0.x, fmaf(wB, a1.x, accf[6]));
    accf[7]  = fmaf(wA, a0.y, fmaf(wB, a1.y, accf[7]));
    a0 = cvt2(Ab.x); a1 = cvt2(Bb.x);
    accf[8]  = fmaf(wA, a0.x, fmaf(wB, a1.x, accf[8]));
    accf[9]  = fmaf(wA, a0.y, fmaf(wB, a1.y, accf[9]));
    a0 = cvt2(Ab.y); a1 = cvt2(Bb.y);
    accf[10] = fmaf(wA, a0.x, fmaf(wB, a1.x, accf[10]));
    accf[11] = fmaf(wA, a0.y, fmaf(wB, a1.y, accf[11]));
    a0 = cvt2(Ab.z); a1 = cvt2(Bb.z);
    accf[12] = fmaf(wA, a0.x, fmaf(wB, a1.x, accf[12]));
    accf[13] = fmaf(wA, a0.y, fmaf(wB, a1.y, accf[13]));
    a0 = cvt2(Ab.w); a1 = cvt2(Bb.w);
    accf[14] = fmaf(wA, a0.x, fmaf(wB, a1.x, accf[14]));
    accf[15] = fmaf(wA, a0.y, fmaf(wB, a1.y, accf[15]));

    Aa = Pa; Ab = Pb; Ba = Qa; Bb = Qb;
    Pa = Ra; Pb = Rb; Qa = Sa; Qb = Sb;
    tAc = tAn; tBc = tBn;
  }
#undef LDH

  #pragma unroll
  for (int i = 0; i < 16; ++i) accf[i] += __shfl_xor(accf[i], 32);
  acc_t  += __shfl_xor(acc_t, 32);
  acc_cc += __shfl_xor(acc_cc, 32);

  __shared__ double s_red[WPB][514];
  if (half == 0) {
    #pragma unroll
    for (int i = 0; i < 8; ++i) {
      s_red[wid][8*sl + i]       = (double)accf[i];
      s_red[wid][256 + 8*sl + i] = (double)accf[8 + i];
    }
  }
  if (l == 0) { s_red[wid][512] = acc_t; s_red[wid][513] = acc_cc; }
  __syncthreads();

  for (int c = threadIdx.x; c < 514; c += BLK) {
    double s = 0.0;
    #pragma unroll
    for (int w2 = 0; w2 < WPB; ++w2) s += s_red[w2][c];
    ws->part[c][blockIdx.x] = s;
  }
}

// ---------------- per-column reduce: one wave per column ----------------
__global__ __launch_bounds__(64)
void colreduce_kernel(Ws* __restrict__ ws)
{
  const int c = blockIdx.x;
  const int l = threadIdx.x;
  const double* col = ws->part[c];
  double s = 0.0;
  #pragma unroll
  for (int k = 0; k < GRID / 64; ++k) s += col[l + 64 * k];
  #pragma unroll
  for (int m = 1; m < 64; m <<= 1) s += __shfl_xor(s, m);
  if (l == 0) ws->colsum[c] = s;
}

// ---------------- final mean (one wave), after the last colreduce ----------------
__global__ __launch_bounds__(64)
void final_kernel(Ws* __restrict__ ws, const float* __restrict__ mprev,
                  float* __restrict__ mnext)
{
  float outm[9];
  compute_mean<false>(ws, mprev, threadIdx.x, outm);
  #pragma unroll
  for (int q = 0; q < 9; ++q) {
    int c = q * 64 + threadIdx.x;
    if (c < D1) mnext[c] = outm[q];
  }
}

__global__ void write_out_kernel(const float* __restrict__ mean, float* __restrict__ out)
{
  int i = threadIdx.x;
  if (i < SDIM) out[i] = mean[i];   // spatial components live at [0..511]
}

extern "C" void kernel_launch(void* const* d_in, const int* in_sizes, int n_in,
                              void* d_out, int out_size, void* d_ws, size_t ws_size,
                              hipStream_t stream)
{
  (void)in_sizes; (void)n_in; (void)out_size; (void)ws_size;
  const float* data = (const float*)d_in[0];
  Ws* ws = (Ws*)d_ws;

  const size_t hoff = (sizeof(Ws) + 255) & ~(size_t)255;
  __half* hdata = (__half*)((char*)d_ws + hoff);

  float* M0 = (float*)((char*)d_ws + offsetof(Ws, meanbuf));        // slot 0
  float* M1 = M0 + 516;                                             // slot 1

  init_kernel<<<dim3(GRID), dim3(BLK), 0, stream>>>(data, hdata, ws);
  colreduce_kernel<<<dim3(514), dim3(64), 0, stream>>>(ws);

  // iter #0: prologue computes mean_0 (INIT semantics) -> writes M0
  iter_kernel<true><<<dim3(GRID), dim3(BLK), 0, stream>>>(hdata, ws, M1, M0);
  colreduce_kernel<<<dim3(514), dim3(64), 0, stream>>>(ws);

  // iters #1..99: prologue computes mean_it from (colsum, mean_{it-1})
  for (int it = 1; it < NITER; ++it) {
    const float* mp = (((it + 1) & 1) == 0) ? M0 : M1;
    float*       mn = ((it & 1) == 0) ? M0 : M1;
    iter_kernel<false><<<dim3(GRID), dim3(BLK), 0, stream>>>(hdata, ws, mp, mn);
    colreduce_kernel<<<dim3(514), dim3(64), 0, stream>>>(ws);
  }

  // mean_100 from the last colreduce + mean_99 (it=99 wrote M1)
  final_kernel<<<dim3(1), dim3(64), 0, stream>>>(ws, M1, M0);
  write_out_kernel<<<dim3(1), dim3(512), 0, stream>>>(M0, (float*)d_out);
}